// Round 4
// baseline (194.011 us; speedup 1.0000x reference)
//
#include <hip/hip_runtime.h>
#include <hip/hip_bf16.h>
#include <stdint.h>

typedef __attribute__((ext_vector_type(8))) short bf16x8;
typedef __attribute__((ext_vector_type(4))) short short4v;
typedef __attribute__((ext_vector_type(4))) float f32x4;

#define LDS3(p) ((__attribute__((address_space(3))) void*)(p))
#define GLB1(p) ((const __attribute__((address_space(1))) void*)(p))

constexpr int Bc = 4;
constexpr int Cc = 256;   // channels (= d_v)
constexpr int Nn = 4096;  // H*W
constexpr int Dq = 32;    // C/8 (= d_qk)
constexpr float L2E = 1.4426950408889634f;

__device__ __forceinline__ short f2b(float x) {
  union { float f; uint32_t u; } v; v.f = x;
  uint32_t r = (v.u + 0x7fffu + ((v.u >> 16) & 1u)) >> 16;  // RNE
  return (short)(r & 0xffffu);
}

// ---------------------------------------------------------------------------
// Kernel 1: transpose-convert f1/f2 [B][C][N] f32 -> [B][N][C] bf16
// ---------------------------------------------------------------------------
__global__ __launch_bounds__(256) void prep_transpose(
    const float* __restrict__ f1, const float* __restrict__ f2,
    short* __restrict__ f1T, short* __restrict__ f2T) {
  __shared__ float tile[64][65];
  const int bx = blockIdx.x;
  const int which = bx >> 10;          // 0: f1, 1: f2
  const int rem = bx & 1023;
  const int b = rem >> 8;
  const int cb = (rem >> 6) & 3;
  const int nb = rem & 63;
  const float* src = which ? f2 : f1;
  short* dst = which ? f2T : f1T;
  const int c0 = cb * 64, n0 = nb * 64;
  const int tid = threadIdx.x;
  const int lane = tid & 63;
  const int row4 = tid >> 6;
#pragma unroll
  for (int i = 0; i < 16; ++i) {
    const int cl = row4 + i * 4;
    tile[cl][lane] = src[(size_t)(b * Cc + c0 + cl) * Nn + n0 + lane];
  }
  __syncthreads();
#pragma unroll
  for (int i = 0; i < 16; ++i) {
    const int nl = row4 + i * 4;
    dst[(size_t)(b * Nn + n0 + nl) * Cc + c0 + lane] = f2b(tile[lane][nl]);
  }
}

// ---------------------------------------------------------------------------
// Kernel 2: convert weights f32 -> bf16 (layouts preserved: [out][in])
// ---------------------------------------------------------------------------
__global__ __launch_bounds__(256) void prep_weights(
    const float* __restrict__ Wq, const float* __restrict__ Wk,
    const float* __restrict__ Wv, short* __restrict__ Wq_b,
    short* __restrict__ Wk_b, short* __restrict__ Wv_b) {
  const int base = (blockIdx.x * 256 + threadIdx.x) * 4;
#pragma unroll
  for (int j = 0; j < 4; ++j) {
    const int idx = base + j;
    if (idx < 8192) Wq_b[idx] = f2b(Wq[idx]);
    else if (idx < 16384) Wk_b[idx - 8192] = f2b(Wk[idx - 8192]);
    else if (idx < 16384 + 65536) Wv_b[idx - 16384] = f2b(Wv[idx - 16384]);
  }
}

// ---------------------------------------------------------------------------
// Kernel 3: projections via MFMA (unchanged, known-good).
// ---------------------------------------------------------------------------
__global__ __launch_bounds__(256) void proj_qkv(
    const short* __restrict__ f1T, const short* __restrict__ f2T,
    const short* __restrict__ Wq_b, const float* __restrict__ bq,
    const short* __restrict__ Wk_b, const float* __restrict__ bk,
    const short* __restrict__ Wv_b, const float* __restrict__ bv,
    short* __restrict__ q_ws, short* __restrict__ k_ws,
    short* __restrict__ v_ws) {
  const int bx = blockIdx.x;
  const int b = bx >> 6;
  const int n0 = (bx & 63) * 64;
  const int tid = threadIdx.x;
  const int w = tid >> 6;
  const int lane = tid & 63;
  const int l16 = lane & 15;
  const int g = lane >> 4;

#pragma unroll
  for (int qk = 0; qk < 2; ++qk) {
    const short* X = qk ? f2T : f1T;
    const short* Wm = qk ? Wk_b : Wq_b;
    const float* bias_p = qk ? bk : bq;
    short* outp = qk ? k_ws : q_ws;
    f32x4 accq[2] = {(f32x4){0.f, 0.f, 0.f, 0.f}, (f32x4){0.f, 0.f, 0.f, 0.f}};
#pragma unroll
    for (int kc = 0; kc < 8; ++kc) {
      const bf16x8 a = *(const bf16x8*)&X[(size_t)(b * Nn + n0 + w * 16 + l16) * Cc + kc * 32 + g * 8];
#pragma unroll
      for (int ob = 0; ob < 2; ++ob) {
        const bf16x8 bb = *(const bf16x8*)&Wm[(ob * 16 + l16) * Cc + kc * 32 + g * 8];
        accq[ob] = __builtin_amdgcn_mfma_f32_16x16x32_bf16(a, bb, accq[ob], 0, 0, 0);
      }
    }
#pragma unroll
    for (int ob = 0; ob < 2; ++ob) {
      const float bias = bias_p[ob * 16 + l16];
#pragma unroll
      for (int r = 0; r < 4; ++r) {
        const int n = n0 + w * 16 + g * 4 + r;
        outp[(size_t)(b * Nn + n) * Dq + ob * 16 + l16] = f2b(accq[ob][r] + bias);
      }
    }
  }

  {
    f32x4 acc[4][4];
#pragma unroll
    for (int ci = 0; ci < 4; ++ci)
#pragma unroll
      for (int nb = 0; nb < 4; ++nb) acc[ci][nb] = (f32x4){0.f, 0.f, 0.f, 0.f};
#pragma unroll
    for (int kc = 0; kc < 8; ++kc) {
      bf16x8 bfr[4];
#pragma unroll
      for (int nb = 0; nb < 4; ++nb)
        bfr[nb] = *(const bf16x8*)&f2T[(size_t)(b * Nn + n0 + nb * 16 + l16) * Cc + kc * 32 + g * 8];
#pragma unroll
      for (int ci = 0; ci < 4; ++ci) {
        const bf16x8 afr = *(const bf16x8*)&Wv_b[((w * 4 + ci) * 16 + l16) * Cc + kc * 32 + g * 8];
#pragma unroll
        for (int nb = 0; nb < 4; ++nb)
          acc[ci][nb] = __builtin_amdgcn_mfma_f32_16x16x32_bf16(afr, bfr[nb], acc[ci][nb], 0, 0, 0);
      }
    }
#pragma unroll
    for (int ci = 0; ci < 4; ++ci) {
#pragma unroll
      for (int r = 0; r < 4; ++r) {
        const int c = (w * 4 + ci) * 16 + g * 4 + r;
        const float bias = bv[c];
#pragma unroll
        for (int nb = 0; nb < 4; ++nb) {
          const int n = n0 + nb * 16 + l16;
          v_ws[(size_t)(b * Cc + c) * Nn + n] = f2b(acc[ci][nb][r] + bias);
        }
      }
    }
  }
}

// ---------------------------------------------------------------------------
// Kernel 4: flash attention v3 — 8 waves (512 thr), wave = 32 rows x 64 ch.
// 2 waves/SIMD for latency hiding; V LDS reads halved (each frag feeds 2 mb).
// Softmax wave-local (c-split waves recompute it; no cross-wave coupling).
// V double-buffered via global_load_lds (linear dest / pre-swizzled source /
// swizzled read). Defer-max THR=8. One barrier per 64-key tile.
// XCD-bijective block swizzle: each XCD works one batch's contiguous range.
// ---------------------------------------------------------------------------
constexpr int NT = 64;
constexpr int NTILES = Nn / NT;        // 64
constexpr int VBUF = 256 * NT * 2;     // 32768 B per buffer ([c][8 granules])
constexpr int POFF = 2 * VBUF;         // 65536
constexpr int PSTRIDE = 4096;          // per-wave P strip: 32 rows x 128 B
constexpr int SBYTES = POFF + 8 * PSTRIDE;  // 98304

__global__ __launch_bounds__(512) void attn_kernel(
    const short* __restrict__ q_ws, const short* __restrict__ k_ws,
    const short* __restrict__ v_ws, const float* __restrict__ feat1,
    const float* __restrict__ gamma_p, float* __restrict__ out) {
  __shared__ __align__(16) char smem[SBYTES];
  const int bx = blockIdx.x;
  const int swz = (bx & 7) * 32 + (bx >> 3);  // XCD-contiguous (256 = 8*32)
  const int b = swz >> 6;
  const int m0 = (swz & 63) * 64;
  const int tid = threadIdx.x;
  const int w = tid >> 6;     // 0..7
  const int rg = w >> 2;      // row group: rows [rg*32, rg*32+32)
  const int cg = w & 3;       // channel group: [cg*64, cg*64+64)
  const int lane = tid & 63;
  const int l16 = lane & 15;
  const int g = lane >> 4;

  // Q frags (B operand): rows m = m0 + rg*32 + mb*16 + l16, k = g*8+j
  bf16x8 qfrag[2];
#pragma unroll
  for (int mb = 0; mb < 2; ++mb)
    qfrag[mb] = *(const bf16x8*)&q_ws[(size_t)(b * Nn + m0 + rg * 32 + mb * 16 + l16) * Dq + g * 8];

  // V stage: 2048 granules of 16B = [256 c][8 key-slots]; 4 per thread.
  // Source pre-swizzled (slot ^= c&7) so linear LDS-DMA lands swizzled image.
  const int cth = tid >> 3;
  const int s7 = tid & 7;
  const short* vsrc[4];
#pragma unroll
  for (int j = 0; j < 4; ++j) {
    const int c = j * 64 + cth;
    vsrc[j] = v_ws + (size_t)(b * Cc + c) * Nn + 8 * (s7 ^ (c & 7));
  }

  const short* kptr = k_ws + (size_t)(b * Nn + l16) * Dq + g * 8;

  f32x4 acc[2][4];  // O[m = rg*32 + mb*16 + 4g+r][c = cg*64 + cb*16 + l16]
#pragma unroll
  for (int mb = 0; mb < 2; ++mb)
#pragma unroll
    for (int cb = 0; cb < 4; ++cb) acc[mb][cb] = (f32x4){0.f, 0.f, 0.f, 0.f};

  float mrun[2] = {-INFINITY, -INFINITY};
  float lrun[2] = {0.f, 0.f};

  // prologue: stage tile 0, prefetch K(0)
#pragma unroll
  for (int j = 0; j < 4; ++j) {
    char* ldst = &smem[(j * 512 + w * 64) * 16];
    __builtin_amdgcn_global_load_lds(GLB1(vsrc[j]), LDS3(ldst), 16, 0, 0);
    vsrc[j] += NT;
  }
  bf16x8 kf[4];
#pragma unroll
  for (int nb = 0; nb < 4; ++nb)
    kf[nb] = *(const bf16x8*)(kptr + nb * 16 * Dq);
  kptr += NT * Dq;

  const int pb = POFF + w * PSTRIDE;
  const int psw = l16 & 7;

  for (int t = 0; t < NTILES; ++t) {
    const int buf = t & 1;
    // ---- S^T = K*Q^T: lane holds S[m][n = t*64 + nb*16 + 4g + r]
    f32x4 s[2][4];
#pragma unroll
    for (int mb = 0; mb < 2; ++mb)
#pragma unroll
      for (int nb = 0; nb < 4; ++nb)
        s[mb][nb] = __builtin_amdgcn_mfma_f32_16x16x32_bf16(
            kf[nb], qfrag[mb], (f32x4){0.f, 0.f, 0.f, 0.f}, 0, 0, 0);

    // ---- wave-local online softmax (rows l16 of each mb half)
    float tmax[2];
#pragma unroll
    for (int mb = 0; mb < 2; ++mb) {
      float tm = fmaxf(fmaxf(s[mb][0][0], s[mb][0][1]), fmaxf(s[mb][0][2], s[mb][0][3]));
#pragma unroll
      for (int nb = 1; nb < 4; ++nb)
        tm = fmaxf(tm, fmaxf(fmaxf(s[mb][nb][0], s[mb][nb][1]),
                             fmaxf(s[mb][nb][2], s[mb][nb][3])));
      tm = fmaxf(tm, __shfl_xor(tm, 16));
      tm = fmaxf(tm, __shfl_xor(tm, 32));
      tmax[mb] = tm;
    }
    if (__any((tmax[0] > mrun[0] + 8.f) || (tmax[1] > mrun[1] + 8.f))) {
#pragma unroll
      for (int mb = 0; mb < 2; ++mb) {
        const float mnew = fmaxf(mrun[mb], tmax[mb]);
        const float scl = exp2f((mrun[mb] - mnew) * L2E);
        float sc[4];
#pragma unroll
        for (int r = 0; r < 4; ++r) sc[r] = __shfl(scl, (g << 2) | r);
#pragma unroll
        for (int cb = 0; cb < 4; ++cb)
#pragma unroll
          for (int r = 0; r < 4; ++r) acc[mb][cb][r] *= sc[r];
        lrun[mb] *= scl;
        mrun[mb] = mnew;
      }
    }
#pragma unroll
    for (int mb = 0; mb < 2; ++mb) {
      float psum = 0.f;
      short4v pk[4];
#pragma unroll
      for (int nb = 0; nb < 4; ++nb)
#pragma unroll
        for (int r = 0; r < 4; ++r) {
          const float p = exp2f((s[mb][nb][r] - mrun[mb]) * L2E);
          psum += p;
          pk[nb][r] = f2b(p);
        }
      psum += __shfl_xor(psum, 16);
      psum += __shfl_xor(psum, 32);
      lrun[mb] += psum;
      // P write (wave-private, swizzled 16B granules; 8B per nb)
#pragma unroll
      for (int nb = 0; nb < 4; ++nb) {
        const int off = (((nb * 2 + (g >> 1)) ^ psw) << 4) | ((g & 1) << 3);
        *(short4v*)&smem[pb + mb * 2048 + l16 * 128 + off] = pk[nb];
      }
    }

    asm volatile("s_waitcnt vmcnt(0)" ::: "memory");  // own V(t) parts done
    __syncthreads();                                   // all parts visible

    if (t + 1 < NTILES) {
#pragma unroll
      for (int j = 0; j < 4; ++j) {
        char* ldst = &smem[(buf ^ 1) * VBUF + (j * 512 + w * 64) * 16];
        __builtin_amdgcn_global_load_lds(GLB1(vsrc[j]), LDS3(ldst), 16, 0, 0);
        vsrc[j] += NT;
      }
#pragma unroll
      for (int nb = 0; nb < 4; ++nb)
        kf[nb] = *(const bf16x8*)(kptr + nb * 16 * Dq);
      kptr += NT * Dq;
    }

    // ---- PV: A = P[mb half][keys], B = V[keys][this wave's 64 channels]
#pragma unroll
    for (int kk = 0; kk < 2; ++kk) {
      bf16x8 pA[2];
#pragma unroll
      for (int mb = 0; mb < 2; ++mb)
        pA[mb] = *(const bf16x8*)&smem[pb + mb * 2048 + l16 * 128 +
                                       (((kk * 4 + g) ^ psw) << 4)];
#pragma unroll
      for (int cb = 0; cb < 4; ++cb) {
        const int c = cg * 64 + cb * 16 + l16;
        const bf16x8 vB = *(const bf16x8*)&smem[buf * VBUF +
            (c * 8 + ((kk * 4 + g) ^ (c & 7))) * 16];
#pragma unroll
        for (int mb = 0; mb < 2; ++mb)
          acc[mb][cb] = __builtin_amdgcn_mfma_f32_16x16x32_bf16(pA[mb], vB, acc[mb][cb], 0, 0, 0);
      }
    }
  }

  // ---- epilogue: per-wave transpose via LDS, out = gamma*O/l + feat1
  __syncthreads();  // done with V/P regions; reuse for transpose
  float inv[2][4];
#pragma unroll
  for (int mb = 0; mb < 2; ++mb)
#pragma unroll
    for (int r = 0; r < 4; ++r)
      inv[mb][r] = 1.f / __shfl(lrun[mb], (g << 2) | r);
  float* ow = (float*)&smem[w * 8448];  // [64 c][33 m] f32, wave-private
#pragma unroll
  for (int mb = 0; mb < 2; ++mb)
#pragma unroll
    for (int cb = 0; cb < 4; ++cb)
#pragma unroll
      for (int r = 0; r < 4; ++r)
        ow[(cb * 16 + l16) * 33 + mb * 16 + 4 * g + r] = acc[mb][cb][r] * inv[mb][r];
  asm volatile("s_waitcnt lgkmcnt(0)" ::: "memory");  // wave-local write->read
  const float gam = gamma_p[0];
  const int mm = lane & 31;
  const int c2 = lane >> 5;
  const size_t obase = (size_t)b * Cc * Nn + (size_t)(m0 + rg * 32 + mm);
#pragma unroll 8
  for (int cc = 0; cc < 32; ++cc) {
    const int c_local = cc * 2 + c2;
    const int c = cg * 64 + c_local;
    const size_t oi = obase + (size_t)c * Nn;
    out[oi] = gam * ow[c_local * 33 + mm] + feat1[oi];
  }
}

// ---------------------------------------------------------------------------
// Launch
// ---------------------------------------------------------------------------
extern "C" void kernel_launch(void* const* d_in, const int* in_sizes, int n_in,
                              void* d_out, int out_size, void* d_ws,
                              size_t ws_size, hipStream_t stream) {
  const float* feat1 = (const float*)d_in[0];
  const float* feat2 = (const float*)d_in[1];
  const float* Wq = (const float*)d_in[2];
  const float* bq = (const float*)d_in[3];
  const float* Wk = (const float*)d_in[4];
  const float* bk = (const float*)d_in[5];
  const float* Wv = (const float*)d_in[6];
  const float* bv = (const float*)d_in[7];
  const float* gamma = (const float*)d_in[8];
  float* out = (float*)d_out;

  char* ws = (char*)d_ws;
  short* f1T = (short*)(ws + 0);           //  8 MiB
  short* f2T = (short*)(ws + 8388608);     //  8 MiB
  short* q_ws = (short*)(ws + 16777216);   //  1 MiB
  short* k_ws = (short*)(ws + 17825792);   //  1 MiB
  short* v_ws = (short*)(ws + 18874368);   //  8 MiB
  short* Wq_b = (short*)(ws + 27262976);   // 16 KiB
  short* Wk_b = (short*)(ws + 27279360);   // 16 KiB
  short* Wv_b = (short*)(ws + 27295744);   // 128 KiB

  prep_transpose<<<2048, 256, 0, stream>>>(feat1, feat2, f1T, f2T);
  prep_weights<<<80, 256, 0, stream>>>(Wq, Wk, Wv, Wq_b, Wk_b, Wv_b);
  proj_qkv<<<256, 256, 0, stream>>>(f1T, f2T, Wq_b, bq, Wk_b, bk, Wv_b, bv,
                                    q_ws, k_ws, v_ws);
  attn_kernel<<<256, 512, 0, stream>>>(q_ws, k_ws, v_ws, feat1, gamma, out);
}

// Round 5
// 117.766 us; speedup vs baseline: 1.6474x; 1.6474x over previous
//
#include <hip/hip_runtime.h>
#include <hip/hip_bf16.h>
#include <stdint.h>

typedef __attribute__((ext_vector_type(8))) short bf16x8;
typedef __attribute__((ext_vector_type(4))) short short4v;
typedef __attribute__((ext_vector_type(4))) float f32x4;

#define LDS3(p) ((__attribute__((address_space(3))) void*)(p))
#define GLB1(p) ((const __attribute__((address_space(1))) void*)(p))

constexpr int Bc = 4;
constexpr int Cc = 256;   // channels (= d_v)
constexpr int Nn = 4096;  // H*W
constexpr int Dq = 32;    // C/8 (= d_qk)
constexpr float L2E = 1.4426950408889634f;

__device__ __forceinline__ short f2b(float x) {
  union { float f; uint32_t u; } v; v.f = x;
  uint32_t r = (v.u + 0x7fffu + ((v.u >> 16) & 1u)) >> 16;  // RNE
  return (short)(r & 0xffffu);
}
__device__ __forceinline__ float b2f(short s) {
  union { uint32_t u; float f; } v; v.u = ((uint32_t)(uint16_t)s) << 16;
  return v.f;
}

// ---------------------------------------------------------------------------
// Kernel 1: transpose-convert f1/f2 [B][C][N] f32 -> [B][N][C] bf16
// ---------------------------------------------------------------------------
__global__ __launch_bounds__(256) void prep_transpose(
    const float* __restrict__ f1, const float* __restrict__ f2,
    short* __restrict__ f1T, short* __restrict__ f2T) {
  __shared__ float tile[64][65];
  const int bx = blockIdx.x;
  const int which = bx >> 10;          // 0: f1, 1: f2
  const int rem = bx & 1023;
  const int b = rem >> 8;
  const int cb = (rem >> 6) & 3;
  const int nb = rem & 63;
  const float* src = which ? f2 : f1;
  short* dst = which ? f2T : f1T;
  const int c0 = cb * 64, n0 = nb * 64;
  const int tid = threadIdx.x;
  const int lane = tid & 63;
  const int row4 = tid >> 6;
#pragma unroll
  for (int i = 0; i < 16; ++i) {
    const int cl = row4 + i * 4;
    tile[cl][lane] = src[(size_t)(b * Cc + c0 + cl) * Nn + n0 + lane];
  }
  __syncthreads();
#pragma unroll
  for (int i = 0; i < 16; ++i) {
    const int nl = row4 + i * 4;
    dst[(size_t)(b * Nn + n0 + nl) * Cc + c0 + lane] = f2b(tile[lane][nl]);
  }
}

// ---------------------------------------------------------------------------
// Kernel 2: convert weights f32 -> bf16 (layouts preserved: [out][in])
// ---------------------------------------------------------------------------
__global__ __launch_bounds__(256) void prep_weights(
    const float* __restrict__ Wq, const float* __restrict__ Wk,
    const float* __restrict__ Wv, short* __restrict__ Wq_b,
    short* __restrict__ Wk_b, short* __restrict__ Wv_b) {
  const int base = (blockIdx.x * 256 + threadIdx.x) * 4;
#pragma unroll
  for (int j = 0; j < 4; ++j) {
    const int idx = base + j;
    if (idx < 8192) Wq_b[idx] = f2b(Wq[idx]);
    else if (idx < 16384) Wk_b[idx - 8192] = f2b(Wk[idx - 8192]);
    else if (idx < 16384 + 65536) Wv_b[idx - 16384] = f2b(Wv[idx - 16384]);
  }
}

// ---------------------------------------------------------------------------
// Kernel 3: projections via MFMA (unchanged, known-good).
// ---------------------------------------------------------------------------
__global__ __launch_bounds__(256) void proj_qkv(
    const short* __restrict__ f1T, const short* __restrict__ f2T,
    const short* __restrict__ Wq_b, const float* __restrict__ bq,
    const short* __restrict__ Wk_b, const float* __restrict__ bk,
    const short* __restrict__ Wv_b, const float* __restrict__ bv,
    short* __restrict__ q_ws, short* __restrict__ k_ws,
    short* __restrict__ v_ws) {
  const int bx = blockIdx.x;
  const int b = bx >> 6;
  const int n0 = (bx & 63) * 64;
  const int tid = threadIdx.x;
  const int w = tid >> 6;
  const int lane = tid & 63;
  const int l16 = lane & 15;
  const int g = lane >> 4;

#pragma unroll
  for (int qk = 0; qk < 2; ++qk) {
    const short* X = qk ? f2T : f1T;
    const short* Wm = qk ? Wk_b : Wq_b;
    const float* bias_p = qk ? bk : bq;
    short* outp = qk ? k_ws : q_ws;
    f32x4 accq[2] = {(f32x4){0.f, 0.f, 0.f, 0.f}, (f32x4){0.f, 0.f, 0.f, 0.f}};
#pragma unroll
    for (int kc = 0; kc < 8; ++kc) {
      const bf16x8 a = *(const bf16x8*)&X[(size_t)(b * Nn + n0 + w * 16 + l16) * Cc + kc * 32 + g * 8];
#pragma unroll
      for (int ob = 0; ob < 2; ++ob) {
        const bf16x8 bb = *(const bf16x8*)&Wm[(ob * 16 + l16) * Cc + kc * 32 + g * 8];
        accq[ob] = __builtin_amdgcn_mfma_f32_16x16x32_bf16(a, bb, accq[ob], 0, 0, 0);
      }
    }
#pragma unroll
    for (int ob = 0; ob < 2; ++ob) {
      const float bias = bias_p[ob * 16 + l16];
#pragma unroll
      for (int r = 0; r < 4; ++r) {
        const int n = n0 + w * 16 + g * 4 + r;
        outp[(size_t)(b * Nn + n) * Dq + ob * 16 + l16] = f2b(accq[ob][r] + bias);
      }
    }
  }

  {
    f32x4 acc[4][4];
#pragma unroll
    for (int ci = 0; ci < 4; ++ci)
#pragma unroll
      for (int nb = 0; nb < 4; ++nb) acc[ci][nb] = (f32x4){0.f, 0.f, 0.f, 0.f};
#pragma unroll
    for (int kc = 0; kc < 8; ++kc) {
      bf16x8 bfr[4];
#pragma unroll
      for (int nb = 0; nb < 4; ++nb)
        bfr[nb] = *(const bf16x8*)&f2T[(size_t)(b * Nn + n0 + nb * 16 + l16) * Cc + kc * 32 + g * 8];
#pragma unroll
      for (int ci = 0; ci < 4; ++ci) {
        const bf16x8 afr = *(const bf16x8*)&Wv_b[((w * 4 + ci) * 16 + l16) * Cc + kc * 32 + g * 8];
#pragma unroll
        for (int nb = 0; nb < 4; ++nb)
          acc[ci][nb] = __builtin_amdgcn_mfma_f32_16x16x32_bf16(afr, bfr[nb], acc[ci][nb], 0, 0, 0);
      }
    }
#pragma unroll
    for (int ci = 0; ci < 4; ++ci) {
#pragma unroll
      for (int r = 0; r < 4; ++r) {
        const int c = (w * 4 + ci) * 16 + g * 4 + r;
        const float bias = bv[c];
#pragma unroll
        for (int nb = 0; nb < 4; ++nb) {
          const int n = n0 + nb * 16 + l16;
          v_ws[(size_t)(b * Cc + c) * Nn + n] = f2b(acc[ci][nb][r] + bias);
        }
      }
    }
  }
}

// ---------------------------------------------------------------------------
// Kernel 4: flash attention, ROW-SPLIT waves (round-2 structure: 4 waves,
// wave = 16 rows x 256 ch, wave-local softmax, zero redundancy), now
// KEY-SPLIT across KS blocks for occupancy (2 blocks/CU -> 2 waves/SIMD).
// KS=2: each block does 2048 keys, writes unnormalized O (bf16) + (m,l);
// combine_kernel merges. KS=1: direct-output fallback (small workspace).
// ---------------------------------------------------------------------------
constexpr int NT = 64;
constexpr int VBUF = 256 * NT * 2;     // 32768 B per buffer ([c][8 granules])
constexpr int POFF = 2 * VBUF;         // 65536; P: 4 waves x 16 rows x 128B
constexpr int SBYTES = POFF + 4 * 2048;  // 73728

template <int KS>
__global__ __launch_bounds__(256) void attn_kernel(
    const short* __restrict__ q_ws, const short* __restrict__ k_ws,
    const short* __restrict__ v_ws, const float* __restrict__ feat1,
    const float* __restrict__ gamma_p, float* __restrict__ out,
    short* __restrict__ Opart, float* __restrict__ mlm,
    float* __restrict__ mll) {
  constexpr int NTK = (Nn / NT) / KS;   // tiles per block
  constexpr int KSPAN = Nn / KS;        // keys per block
  __shared__ __align__(16) char smem[SBYTES];
  const int bx = blockIdx.x;
  // XCD-bijective swizzle: each XCD gets a contiguous swz-chunk (one split/
  // batch slice -> its K/V half is per-XCD L2 resident).
  const int swz = (bx & 7) * (32 * KS) + (bx >> 3);
  const int ks = swz >> 8;              // 0 for KS=1
  const int rem = swz & 255;
  const int b = rem >> 6;
  const int m0 = (rem & 63) * 64;
  const int n0 = ks * KSPAN;
  const int tid = threadIdx.x;
  const int w = tid >> 6;
  const int lane = tid & 63;
  const int l16 = lane & 15;
  const int g = lane >> 4;

  // Q frag (B operand): rows m = m0 + w*16 + l16, k = g*8+j
  const bf16x8 qfrag =
      *(const bf16x8*)&q_ws[(size_t)(b * Nn + m0 + w * 16 + l16) * Dq + g * 8];

  // V stage: thread owns granule (c = j*32 + tid>>3, q = tid&7); source
  // pre-swizzled by q ^= (c&7) so linear LDS-DMA lands the swizzled image.
  const int cth = tid >> 3;
  const int s7 = tid & 7;
  const short* vsrc[8];
#pragma unroll
  for (int j = 0; j < 8; ++j) {
    const int c = j * 32 + cth;
    vsrc[j] = v_ws + (size_t)(b * Cc + c) * Nn + n0 + 8 * (s7 ^ (c & 7));
  }

  const short* kptr = k_ws + (size_t)(b * Nn + n0 + l16) * Dq + g * 8;

  f32x4 acc[16];  // O[m_local = 4g+r][c = cb*16 + l16]
#pragma unroll
  for (int i = 0; i < 16; ++i) acc[i] = (f32x4){0.f, 0.f, 0.f, 0.f};

  float mrun = -INFINITY, lrun = 0.f;

  // prologue: stage tile 0, prefetch K(0)
#pragma unroll
  for (int j = 0; j < 8; ++j) {
    char* ldst = &smem[(j * 256 + w * 64) * 16];
    __builtin_amdgcn_global_load_lds(GLB1(vsrc[j]), LDS3(ldst), 16, 0, 0);
    vsrc[j] += NT;
  }
  bf16x8 kf[4];
#pragma unroll
  for (int nb = 0; nb < 4; ++nb)
    kf[nb] = *(const bf16x8*)(kptr + nb * 16 * Dq);
  kptr += NT * Dq;

  const int pbase = POFF + w * 2048 + l16 * 128;
  const int psw = l16 & 7;

  for (int t = 0; t < NTK; ++t) {
    const int buf = t & 1;
    // ---- S^T = K*Q^T: lane holds S[m=l16][n = n0 + t*64 + nb*16 + 4g + r]
    f32x4 s[4];
#pragma unroll
    for (int nb = 0; nb < 4; ++nb)
      s[nb] = __builtin_amdgcn_mfma_f32_16x16x32_bf16(
          kf[nb], qfrag, (f32x4){0.f, 0.f, 0.f, 0.f}, 0, 0, 0);

    // ---- wave-local online softmax (row m = l16; reduce over g)
    float tmax = fmaxf(fmaxf(s[0][0], s[0][1]), fmaxf(s[0][2], s[0][3]));
#pragma unroll
    for (int nb = 1; nb < 4; ++nb)
      tmax = fmaxf(tmax, fmaxf(fmaxf(s[nb][0], s[nb][1]), fmaxf(s[nb][2], s[nb][3])));
    tmax = fmaxf(tmax, __shfl_xor(tmax, 16));
    tmax = fmaxf(tmax, __shfl_xor(tmax, 32));
    if (__any(tmax > mrun + 8.f)) {       // defer-max: rescale rarely
      const float mnew = fmaxf(mrun, tmax);
      const float scl = exp2f((mrun - mnew) * L2E);
      float sc[4];
#pragma unroll
      for (int r = 0; r < 4; ++r) sc[r] = __shfl(scl, (g << 2) | r);
#pragma unroll
      for (int cb = 0; cb < 16; ++cb)
#pragma unroll
        for (int r = 0; r < 4; ++r) acc[cb][r] *= sc[r];
      lrun *= scl;
      mrun = mnew;
    }
    float psum = 0.f;
    short4v pk[4];
#pragma unroll
    for (int nb = 0; nb < 4; ++nb)
#pragma unroll
      for (int r = 0; r < 4; ++r) {
        const float p = exp2f((s[nb][r] - mrun) * L2E);
        psum += p;
        pk[nb][r] = f2b(p);
      }
    psum += __shfl_xor(psum, 16);
    psum += __shfl_xor(psum, 32);
    lrun += psum;

    // ---- P write (wave-private, swizzled 16B granules)
#pragma unroll
    for (int nb = 0; nb < 4; ++nb) {
      const int off = (((nb * 2 + (g >> 1)) ^ psw) << 4) | ((g & 1) << 3);
      *(short4v*)&smem[pbase + off] = pk[nb];
    }

    asm volatile("s_waitcnt vmcnt(0)" ::: "memory");  // own V(t) parts done
    __syncthreads();                                   // all parts visible

    if (t + 1 < NTK) {
#pragma unroll
      for (int j = 0; j < 8; ++j) {
        char* ldst = &smem[(buf ^ 1) * VBUF + (j * 256 + w * 64) * 16];
        __builtin_amdgcn_global_load_lds(GLB1(vsrc[j]), LDS3(ldst), 16, 0, 0);
        vsrc[j] += NT;
      }
#pragma unroll
      for (int nb = 0; nb < 4; ++nb)
        kf[nb] = *(const bf16x8*)(kptr + nb * 16 * Dq);
      kptr += NT * Dq;
    }

    // ---- PV: A = P[16 rows][64 keys] (2 k-frags), B = V[keys][256 c]
    bf16x8 pA[2];
#pragma unroll
    for (int kk = 0; kk < 2; ++kk)
      pA[kk] = *(const bf16x8*)&smem[pbase + (((kk * 4 + g) ^ psw) << 4)];
#pragma unroll
    for (int kk = 0; kk < 2; ++kk)
#pragma unroll
      for (int cb = 0; cb < 16; ++cb) {
        const int c = cb * 16 + l16;
        const bf16x8 vB = *(const bf16x8*)&smem[buf * VBUF + c * 128 +
                                                (((kk * 4 + g) ^ psw) << 4)];
        acc[cb] = __builtin_amdgcn_mfma_f32_16x16x32_bf16(pA[kk], vB, acc[cb], 0, 0, 0);
      }
  }

  if constexpr (KS > 1) {
    // ---- partial epilogue: unnormalized O (bf16, [ks][b][m][c]) + (m,l)
    if (lane < 16) {
      const int m = m0 + w * 16 + lane;
      mlm[(size_t)(ks * Bc + b) * Nn + m] = mrun;
      mll[(size_t)(ks * Bc + b) * Nn + m] = lrun;
    }
#pragma unroll
    for (int cb = 0; cb < 16; ++cb)
#pragma unroll
      for (int r = 0; r < 4; ++r) {
        const size_t oi =
            ((size_t)(ks * Bc + b) * Nn + m0 + w * 16 + 4 * g + r) * Cc +
            cb * 16 + l16;
        Opart[oi] = f2b(acc[cb][r]);
      }
  } else {
    // ---- direct epilogue: per-wave transpose via LDS, out = g*O/l + feat1
    __syncthreads();  // everyone done reading V LDS
    float inv[4];
#pragma unroll
    for (int r = 0; r < 4; ++r) inv[r] = 1.f / __shfl(lrun, (g << 2) | r);
    float* olds = (float*)&smem[w * 16448];  // [16 m][257 c]
#pragma unroll
    for (int cb = 0; cb < 16; ++cb)
#pragma unroll
      for (int r = 0; r < 4; ++r)
        olds[(4 * g + r) * 257 + cb * 16 + l16] = acc[cb][r] * inv[r];
    asm volatile("s_waitcnt lgkmcnt(0)" ::: "memory");
    const float gam = gamma_p[0];
    const int c4 = lane >> 4;
    const int mm = lane & 15;
    const size_t obase = (size_t)b * Cc * Nn + (size_t)(m0 + w * 16 + mm);
#pragma unroll 8
    for (int cc = 0; cc < 64; ++cc) {
      const int c = cc * 4 + c4;
      const size_t oi = obase + (size_t)c * Nn;
      out[oi] = gam * olds[mm * 257 + c] + feat1[oi];
    }
  }
}

// ---------------------------------------------------------------------------
// Kernel 5: combine 2 key-splits + transpose + residual.
// grid = B * (N/64) * (C/64) = 1024 blocks, 256 threads.
// out[b][c][m] = gamma * (O1[m][c]*a1[m] + O2[m][c]*a2[m]) + feat1[b][c][m]
// where a_i = exp2((m_i - m*)*L2E) / l_comb.
// ---------------------------------------------------------------------------
__global__ __launch_bounds__(256) void combine_kernel(
    const short* __restrict__ Opart, const float* __restrict__ mlm,
    const float* __restrict__ mll, const float* __restrict__ feat1,
    const float* __restrict__ gamma_p, float* __restrict__ out) {
  __shared__ float a1s[64], a2s[64];
  __shared__ float tile[64][65];
  const int bx = blockIdx.x;      // b*256 + mt*4 + ct
  const int b = bx >> 8;
  const int mt = (bx >> 2) & 63;
  const int ct = bx & 3;
  const int m0 = mt * 64, c0 = ct * 64;
  const int tid = threadIdx.x;
  if (tid < 64) {
    const int m = m0 + tid;
    const float m1 = mlm[(size_t)(0 * Bc + b) * Nn + m];
    const float m2 = mlm[(size_t)(1 * Bc + b) * Nn + m];
    const float l1 = mll[(size_t)(0 * Bc + b) * Nn + m];
    const float l2 = mll[(size_t)(1 * Bc + b) * Nn + m];
    const float ms = fmaxf(m1, m2);
    const float e1 = exp2f((m1 - ms) * L2E);
    const float e2 = exp2f((m2 - ms) * L2E);
    const float inv = 1.f / (l1 * e1 + l2 * e2);
    a1s[tid] = e1 * inv;
    a2s[tid] = e2 * inv;
  }
  __syncthreads();
  const int rr = tid >> 6;   // 0..3
  const int cl = tid & 63;
#pragma unroll
  for (int i = 0; i < 16; ++i) {
    const int ml = rr + i * 4;
    const size_t i1 = ((size_t)(0 * Bc + b) * Nn + m0 + ml) * Cc + c0 + cl;
    const size_t i2 = ((size_t)(1 * Bc + b) * Nn + m0 + ml) * Cc + c0 + cl;
    tile[ml][cl] = b2f(Opart[i1]) * a1s[ml] + b2f(Opart[i2]) * a2s[ml];
  }
  __syncthreads();
  const float gam = gamma_p[0];
#pragma unroll
  for (int i = 0; i < 16; ++i) {
    const int cll = rr + i * 4;
    const size_t oi = ((size_t)b * Cc + c0 + cll) * Nn + m0 + cl;
    out[oi] = gam * tile[cl][cll] + feat1[oi];
  }
}

// ---------------------------------------------------------------------------
// Launch
// ---------------------------------------------------------------------------
extern "C" void kernel_launch(void* const* d_in, const int* in_sizes, int n_in,
                              void* d_out, int out_size, void* d_ws,
                              size_t ws_size, hipStream_t stream) {
  const float* feat1 = (const float*)d_in[0];
  const float* feat2 = (const float*)d_in[1];
  const float* Wq = (const float*)d_in[2];
  const float* bq = (const float*)d_in[3];
  const float* Wk = (const float*)d_in[4];
  const float* bk = (const float*)d_in[5];
  const float* Wv = (const float*)d_in[6];
  const float* bv = (const float*)d_in[7];
  const float* gamma = (const float*)d_in[8];
  float* out = (float*)d_out;

  char* ws = (char*)d_ws;
  short* f1T = (short*)(ws + 0);           //  8 MiB
  short* f2T = (short*)(ws + 8388608);     //  8 MiB
  short* q_ws = (short*)(ws + 16777216);   //  1 MiB
  short* k_ws = (short*)(ws + 17825792);   //  1 MiB
  short* v_ws = (short*)(ws + 18874368);   //  8 MiB
  short* Wq_b = (short*)(ws + 27262976);   // 16 KiB
  short* Wk_b = (short*)(ws + 27279360);   // 16 KiB
  short* Wv_b = (short*)(ws + 27295744);   // 128 KiB
  // key-split partials (only used when workspace is large enough):
  short* Opart = (short*)(ws + 27426816);  // 2*4*4096*256 bf16 = 16 MiB
  float* mlm   = (float*)(ws + 44204032);  // 128 KiB
  float* mll   = (float*)(ws + 44335104);  // 128 KiB
  const size_t need2 = 44466176;

  prep_transpose<<<2048, 256, 0, stream>>>(feat1, feat2, f1T, f2T);
  prep_weights<<<80, 256, 0, stream>>>(Wq, Wk, Wv, Wq_b, Wk_b, Wv_b);
  proj_qkv<<<256, 256, 0, stream>>>(f1T, f2T, Wq_b, bq, Wk_b, bk, Wv_b, bv,
                                    q_ws, k_ws, v_ws);
  if (ws_size >= need2) {
    attn_kernel<2><<<512, 256, 0, stream>>>(q_ws, k_ws, v_ws, feat1, gamma,
                                            out, Opart, mlm, mll);
    combine_kernel<<<1024, 256, 0, stream>>>(Opart, mlm, mll, feat1, gamma,
                                             out);
  } else {
    attn_kernel<1><<<256, 256, 0, stream>>>(q_ws, k_ws, v_ws, feat1, gamma,
                                            out, nullptr, nullptr, nullptr);
  }
}

// Round 7
// 102.635 us; speedup vs baseline: 1.8903x; 1.1474x over previous
//
#include <hip/hip_runtime.h>
#include <hip/hip_bf16.h>
#include <stdint.h>

typedef __attribute__((ext_vector_type(8))) short bf16x8;
typedef __attribute__((ext_vector_type(4))) short short4v;
typedef __attribute__((ext_vector_type(4))) float f32x4;
typedef __attribute__((ext_vector_type(16))) float f32x16;
typedef __attribute__((ext_vector_type(4))) unsigned uint4v;

#define LDS3(p) ((__attribute__((address_space(3))) void*)(p))
#define GLB1(p) ((const __attribute__((address_space(1))) void*)(p))

constexpr int Bc = 4;
constexpr int Cc = 256;   // channels (= d_v)
constexpr int Nn = 4096;  // H*W
constexpr int Dq = 32;    // C/8 (= d_qk)
constexpr float L2E = 1.4426950408889634f;

__device__ __forceinline__ short f2b(float x) {
  union { float f; uint32_t u; } v; v.f = x;
  uint32_t r = (v.u + 0x7fffu + ((v.u >> 16) & 1u)) >> 16;  // RNE
  return (short)(r & 0xffffu);
}
__device__ __forceinline__ float b2f(short s) {
  union { uint32_t u; float f; } v; v.u = ((uint32_t)(uint16_t)s) << 16;
  return v.f;
}
__device__ __forceinline__ unsigned fb(float x) {
  union { float f; unsigned u; } v; v.f = x; return v.u;
}

// ---------------------------------------------------------------------------
// Kernel 1: transpose-convert f1/f2 [B][C][N] f32 -> [B][N][C] bf16
// ---------------------------------------------------------------------------
__global__ __launch_bounds__(256) void prep_transpose(
    const float* __restrict__ f1, const float* __restrict__ f2,
    short* __restrict__ f1T, short* __restrict__ f2T) {
  __shared__ float tile[64][65];
  const int bx = blockIdx.x;
  const int which = bx >> 10;          // 0: f1, 1: f2
  const int rem = bx & 1023;
  const int b = rem >> 8;
  const int cb = (rem >> 6) & 3;
  const int nb = rem & 63;
  const float* src = which ? f2 : f1;
  short* dst = which ? f2T : f1T;
  const int c0 = cb * 64, n0 = nb * 64;
  const int tid = threadIdx.x;
  const int lane = tid & 63;
  const int row4 = tid >> 6;
#pragma unroll
  for (int i = 0; i < 16; ++i) {
    const int cl = row4 + i * 4;
    tile[cl][lane] = src[(size_t)(b * Cc + c0 + cl) * Nn + n0 + lane];
  }
  __syncthreads();
#pragma unroll
  for (int i = 0; i < 16; ++i) {
    const int nl = row4 + i * 4;
    dst[(size_t)(b * Nn + n0 + nl) * Cc + c0 + lane] = f2b(tile[lane][nl]);
  }
}

// ---------------------------------------------------------------------------
// Kernel 2: convert weights f32 -> bf16 (layouts preserved: [out][in])
// ---------------------------------------------------------------------------
__global__ __launch_bounds__(256) void prep_weights(
    const float* __restrict__ Wq, const float* __restrict__ Wk,
    const float* __restrict__ Wv, short* __restrict__ Wq_b,
    short* __restrict__ Wk_b, short* __restrict__ Wv_b) {
  const int base = (blockIdx.x * 256 + threadIdx.x) * 4;
#pragma unroll
  for (int j = 0; j < 4; ++j) {
    const int idx = base + j;
    if (idx < 8192) Wq_b[idx] = f2b(Wq[idx]);
    else if (idx < 16384) Wk_b[idx - 8192] = f2b(Wk[idx - 8192]);
    else if (idx < 16384 + 65536) Wv_b[idx - 16384] = f2b(Wv[idx - 16384]);
  }
}

// ---------------------------------------------------------------------------
// Kernel 3: projections via MFMA (unchanged, known-good).
// ---------------------------------------------------------------------------
__global__ __launch_bounds__(256) void proj_qkv(
    const short* __restrict__ f1T, const short* __restrict__ f2T,
    const short* __restrict__ Wq_b, const float* __restrict__ bq,
    const short* __restrict__ Wk_b, const float* __restrict__ bk,
    const short* __restrict__ Wv_b, const float* __restrict__ bv,
    short* __restrict__ q_ws, short* __restrict__ k_ws,
    short* __restrict__ v_ws) {
  const int bx = blockIdx.x;
  const int b = bx >> 6;
  const int n0 = (bx & 63) * 64;
  const int tid = threadIdx.x;
  const int w = tid >> 6;
  const int lane = tid & 63;
  const int l16 = lane & 15;
  const int g = lane >> 4;

#pragma unroll
  for (int qk = 0; qk < 2; ++qk) {
    const short* X = qk ? f2T : f1T;
    const short* Wm = qk ? Wk_b : Wq_b;
    const float* bias_p = qk ? bk : bq;
    short* outp = qk ? k_ws : q_ws;
    f32x4 accq[2] = {(f32x4){0.f, 0.f, 0.f, 0.f}, (f32x4){0.f, 0.f, 0.f, 0.f}};
#pragma unroll
    for (int kc = 0; kc < 8; ++kc) {
      const bf16x8 a = *(const bf16x8*)&X[(size_t)(b * Nn + n0 + w * 16 + l16) * Cc + kc * 32 + g * 8];
#pragma unroll
      for (int ob = 0; ob < 2; ++ob) {
        const bf16x8 bb = *(const bf16x8*)&Wm[(ob * 16 + l16) * Cc + kc * 32 + g * 8];
        accq[ob] = __builtin_amdgcn_mfma_f32_16x16x32_bf16(a, bb, accq[ob], 0, 0, 0);
      }
    }
#pragma unroll
    for (int ob = 0; ob < 2; ++ob) {
      const float bias = bias_p[ob * 16 + l16];
#pragma unroll
      for (int r = 0; r < 4; ++r) {
        const int n = n0 + w * 16 + g * 4 + r;
        outp[(size_t)(b * Nn + n) * Dq + ob * 16 + l16] = f2b(accq[ob][r] + bias);
      }
    }
  }

  {
    f32x4 acc[4][4];
#pragma unroll
    for (int ci = 0; ci < 4; ++ci)
#pragma unroll
      for (int nb = 0; nb < 4; ++nb) acc[ci][nb] = (f32x4){0.f, 0.f, 0.f, 0.f};
#pragma unroll
    for (int kc = 0; kc < 8; ++kc) {
      bf16x8 bfr[4];
#pragma unroll
      for (int nb = 0; nb < 4; ++nb)
        bfr[nb] = *(const bf16x8*)&f2T[(size_t)(b * Nn + n0 + nb * 16 + l16) * Cc + kc * 32 + g * 8];
#pragma unroll
      for (int ci = 0; ci < 4; ++ci) {
        const bf16x8 afr = *(const bf16x8*)&Wv_b[((w * 4 + ci) * 16 + l16) * Cc + kc * 32 + g * 8];
#pragma unroll
        for (int nb = 0; nb < 4; ++nb)
          acc[ci][nb] = __builtin_amdgcn_mfma_f32_16x16x32_bf16(afr, bfr[nb], acc[ci][nb], 0, 0, 0);
      }
    }
#pragma unroll
    for (int ci = 0; ci < 4; ++ci) {
#pragma unroll
      for (int r = 0; r < 4; ++r) {
        const int c = (w * 4 + ci) * 16 + g * 4 + r;
        const float bias = bv[c];
#pragma unroll
        for (int nb = 0; nb < 4; ++nb) {
          const int n = n0 + nb * 16 + l16;
          v_ws[(size_t)(b * Cc + c) * Nn + n] = f2b(acc[ci][nb][r] + bias);
        }
      }
    }
  }
}

// ---------------------------------------------------------------------------
// Kernel 4: flash attention, 32x32 MFMA, in-register P, NO cross-lane P
// exchange: K rows are loaded at rho(l31) (bits 2<->3 swapped), so the S^T
// C/D key pattern crow(r,h)=(r&3)+8(r>>2)+4h lands such that the packed
// pu[4f..4f+3] directly form the PV A-operand (keys 16f+8h+j), matching the
// V LDS granule at slot 2f+h. Softmax is permutation-invariant per tile.
// Block = 128 q-rows (4 waves x 32 rows), key-split KS across blocks.
// V dbuf in LDS via global_load_lds (linear dest / pre-swizzled source /
// swizzled read). Defer-max THR=8. 1 barrier/tile.
// Epilogue: per-wave LDS transpose -> Opart [ks][b][c][m] bf16 + (m, l).
// ---------------------------------------------------------------------------
constexpr int NT = 64;
constexpr int VBUF = 256 * NT * 2;   // 32768 B per buffer ([c][8 granules])
constexpr int SBYTES = 2 * VBUF;     // 65536

template <int KS>
__global__ __launch_bounds__(256, 2) void attn_kernel(
    const short* __restrict__ q_ws, const short* __restrict__ k_ws,
    const short* __restrict__ v_ws, short* __restrict__ Opart,
    float* __restrict__ mlm, short* __restrict__ mll) {
  constexpr int KSPAN = Nn / KS;
  constexpr int NTILES = KSPAN / NT;
  __shared__ __align__(16) char smem[SBYTES];
  const int bx = blockIdx.x;
  const int swz = (bx & 7) * (16 * KS) + (bx >> 3);  // XCD-bijective
  const int ks = swz >> 7;
  const int rem = swz & 127;
  const int b = rem >> 5;
  const int m0 = (rem & 31) * 128;
  const int n0 = ks * KSPAN;
  const int tid = threadIdx.x;
  const int w = tid >> 6;
  const int lane = tid & 63;
  const int l31 = lane & 31;
  const int h = lane >> 5;

  // Q B-frags (persist): col m = m0 + w*32 + l31, k = s*16 + 8h + j
  const short* qbase = q_ws + (size_t)(b * Nn + m0 + w * 32 + l31) * Dq + h * 8;
  const bf16x8 qf0 = *(const bf16x8*)(qbase);
  const bf16x8 qf1 = *(const bf16x8*)(qbase + 16);

  // K A-frags at permuted row rho(l31) = swap bits 2<->3 (see header comment)
  const int kswap = (l31 & 0x13) | ((l31 & 4) << 1) | ((l31 & 8) >> 1);
  const short* kptr = k_ws + (size_t)(b * Nn + n0 + kswap) * Dq + h * 8;

  // V stage: granule (c = j*32 + tid>>3, slot = tid&7); source pre-swizzled
  // (key-block ^= c&7) so the linear LDS-DMA lands the swizzled image.
  const int cth = tid >> 3;
  const int c7 = cth & 7;
  const int koff = 8 * ((tid & 7) ^ c7);
  const short* vsrc[8];
#pragma unroll
  for (int j = 0; j < 8; ++j)
    vsrc[j] = v_ws + (size_t)(b * Cc + j * 32 + cth) * Nn + n0 + koff;

  f32x16 acc[8] = {};  // O[m-pattern reg][c = cb*32 + l31]
  float mrun = -INFINITY, lrun = 0.f;

  // prologue: stage tile 0, prefetch K(0)
#pragma unroll
  for (int j = 0; j < 8; ++j) {
    char* ldst = &smem[(j * 256 + tid) * 16];
    __builtin_amdgcn_global_load_lds(GLB1(vsrc[j]), LDS3(ldst), 16, 0, 0);
    vsrc[j] += NT;
  }
  bf16x8 kf[4];  // [nb*2 + s]
#pragma unroll
  for (int nb = 0; nb < 2; ++nb)
#pragma unroll
    for (int s = 0; s < 2; ++s)
      kf[nb * 2 + s] = *(const bf16x8*)(kptr + nb * 32 * Dq + s * 16);
  kptr += NT * Dq;

  const f32x16 Z = {};
  for (int t = 0; t < NTILES; ++t) {
    const int buf = t & 1;
    // ---- S^T = K*Q^T: lane owns row m = l31; key rows are rho-permuted
    f32x16 sa[2];
    sa[0] = __builtin_amdgcn_mfma_f32_32x32x16_bf16(kf[0], qf0, Z, 0, 0, 0);
    sa[0] = __builtin_amdgcn_mfma_f32_32x32x16_bf16(kf[1], qf1, sa[0], 0, 0, 0);
    sa[1] = __builtin_amdgcn_mfma_f32_32x32x16_bf16(kf[2], qf0, Z, 0, 0, 0);
    sa[1] = __builtin_amdgcn_mfma_f32_32x32x16_bf16(kf[3], qf1, sa[1], 0, 0, 0);

    // ---- wave-local online softmax (lane = one row; partner lane +32)
    float tmax = sa[0][0];
#pragma unroll
    for (int r = 1; r < 16; ++r) tmax = fmaxf(tmax, sa[0][r]);
#pragma unroll
    for (int r = 0; r < 16; ++r) tmax = fmaxf(tmax, sa[1][r]);
    tmax = fmaxf(tmax, __shfl_xor(tmax, 32));
    if (__any(tmax > mrun + 8.f)) {   // defer-max: rescale rarely
      const float mnew = fmaxf(mrun, tmax);
      const float scl = exp2f((mrun - mnew) * L2E);
      float sv[16];
#pragma unroll
      for (int r = 0; r < 16; ++r)
        sv[r] = __shfl(scl, (r & 3) + 8 * (r >> 2) + 4 * h);
#pragma unroll
      for (int cb = 0; cb < 8; ++cb)
#pragma unroll
        for (int r = 0; r < 16; ++r) acc[cb][r] *= sv[r];
      lrun *= scl;
      mrun = mnew;
    }
    const float nml = -mrun * L2E;
    float psum = 0.f;
    unsigned pu[16];
#pragma unroll
    for (int nb = 0; nb < 2; ++nb)
#pragma unroll
      for (int q = 0; q < 8; ++q) {
        const float p0 = exp2f(fmaf(sa[nb][2 * q], L2E, nml));
        const float p1 = exp2f(fmaf(sa[nb][2 * q + 1], L2E, nml));
        psum += p0 + p1;
        pu[nb * 8 + q] = __builtin_amdgcn_perm(fb(p1), fb(p0), 0x07060302u);
      }
    psum += __shfl_xor(psum, 32);
    lrun += psum;

    asm volatile("s_waitcnt vmcnt(0)" ::: "memory");  // V(t) staged
    __syncthreads();

    if (t + 1 < NTILES) {
#pragma unroll
      for (int j = 0; j < 8; ++j) {
        char* ldst = &smem[(buf ^ 1) * VBUF + (j * 256 + tid) * 16];
        __builtin_amdgcn_global_load_lds(GLB1(vsrc[j]), LDS3(ldst), 16, 0, 0);
        vsrc[j] += NT;
      }
#pragma unroll
      for (int nb = 0; nb < 2; ++nb)
#pragma unroll
        for (int s = 0; s < 2; ++s)
          kf[nb * 2 + s] = *(const bf16x8*)(kptr + nb * 32 * Dq + s * 16);
      kptr += NT * Dq;
    }

    // ---- PV: A = pu frags (direct, thanks to rho), B = V[k16][c32] LDS
    const int sb = buf * VBUF;
#pragma unroll
    for (int f = 0; f < 4; ++f) {     // kstep: keys 16f .. 16f+15
      const uint4v au = {pu[4 * f], pu[4 * f + 1], pu[4 * f + 2], pu[4 * f + 3]};
      const bf16x8 A = __builtin_bit_cast(bf16x8, au);
      const char* vbase =
          &smem[sb + l31 * 128 + ((((f << 1) + h) ^ (l31 & 7)) << 4)];
#pragma unroll
      for (int cb = 0; cb < 8; ++cb) {
        const bf16x8 vB = *(const bf16x8*)(vbase + cb * 4096);
        acc[cb] = __builtin_amdgcn_mfma_f32_32x32x16_bf16(A, vB, acc[cb], 0, 0, 0);
      }
    }
  }

  // ---- epilogue: (m,l) + per-wave LDS transpose -> Opart [ks][b][c][m]
  __syncthreads();  // all PV done; VBUF reusable as transpose strips
  if (h == 0) {
    const int m = m0 + w * 32 + l31;
    mlm[(size_t)(ks * Bc + b) * Nn + m] = mrun;
    mll[(size_t)(ks * Bc + b) * Nn + m] = f2b(lrun);
  }
  char* strip = smem + w * 10240;  // [128 c][80 B] per wave, private
#pragma unroll
  for (int ph = 0; ph < 2; ++ph) {
#pragma unroll
    for (int cb2 = 0; cb2 < 4; ++cb2) {
      const int cb = ph * 4 + cb2;
      const int cs = cb2 * 32 + l31;
#pragma unroll
      for (int q = 0; q < 8; ++q) {   // m-pairs: regs (2q, 2q+1)
        const int mloc = ((2 * q) & 3) + 8 * (q >> 1) + 4 * h;
        const unsigned pv = __builtin_amdgcn_perm(
            fb(acc[cb][2 * q + 1]), fb(acc[cb][2 * q]), 0x07060302u);
        *(unsigned*)(strip + cs * 80 + mloc * 2) = pv;
      }
    }
    asm volatile("s_waitcnt lgkmcnt(0)" ::: "memory");
#pragma unroll
    for (int i = 0; i < 8; ++i) {
      const int gi = i * 64 + lane;
      const int cs = gi >> 2, gq = gi & 3;
      const uint4v vv = *(const uint4v*)(strip + cs * 80 + gq * 16);
      const int cg = ph * 128 + cs;
      const size_t off =
          ((size_t)(ks * Bc + b) * Cc + cg) * Nn + m0 + w * 32 + gq * 8;
      *(uint4v*)&Opart[off] = vv;
    }
    asm volatile("s_waitcnt lgkmcnt(0)" ::: "memory");
  }
}

// ---------------------------------------------------------------------------
// Kernel 5: combine KS key-splits + residual (pure streaming, no transpose).
// grid = B * (N/64) blocks; out[b][c][m] = gam * Sum_ks O_ks[c][m]*a_ks[m]
//                                          + feat1[b][c][m]
// ---------------------------------------------------------------------------
template <int KS>
__global__ __launch_bounds__(256) void combine_kernel(
    const short* __restrict__ Opart, const float* __restrict__ mlm,
    const short* __restrict__ mll, const float* __restrict__ feat1,
    const float* __restrict__ gamma_p, float* __restrict__ out) {
  __shared__ float aLDS[KS][64];
  const int bx = blockIdx.x;       // b*64 + mrange
  const int b = bx >> 6;
  const int m0 = (bx & 63) * 64;
  const int tid = threadIdx.x;
  if (tid < 64) {
    const int m = m0 + tid;
    float mm[KS], ll[KS], ms = -INFINITY;
#pragma unroll
    for (int ks = 0; ks < KS; ++ks) {
      mm[ks] = mlm[(size_t)(ks * Bc + b) * Nn + m];
      ll[ks] = b2f(mll[(size_t)(ks * Bc + b) * Nn + m]);
      ms = fmaxf(ms, mm[ks]);
    }
    float es[KS], lsum = 0.f;
#pragma unroll
    for (int ks = 0; ks < KS; ++ks) {
      es[ks] = exp2f((mm[ks] - ms) * L2E);
      lsum += ll[ks] * es[ks];
    }
    const float inv = 1.f / lsum;
#pragma unroll
    for (int ks = 0; ks < KS; ++ks) aLDS[ks][tid] = es[ks] * inv;
  }
  __syncthreads();
  const int mg = tid & 7;          // m-granule (8 m's)
  const int cb = tid >> 3;         // 0..31
  float aks[KS][8];
#pragma unroll
  for (int ks = 0; ks < KS; ++ks)
#pragma unroll
    for (int j = 0; j < 8; ++j) aks[ks][j] = aLDS[ks][mg * 8 + j];
  const float gam = gamma_p[0];
#pragma unroll 2
  for (int i = 0; i < 8; ++i) {
    const int c = cb + i * 32;
    float v[8] = {0.f, 0.f, 0.f, 0.f, 0.f, 0.f, 0.f, 0.f};
#pragma unroll
    for (int ks = 0; ks < KS; ++ks) {
      const bf16x8 ov = *(const bf16x8*)
          &Opart[((size_t)(ks * Bc + b) * Cc + c) * Nn + m0 + mg * 8];
#pragma unroll
      for (int j = 0; j < 8; ++j) v[j] += b2f(ov[j]) * aks[ks][j];
    }
    const size_t base = ((size_t)(b * Cc + c)) * Nn + m0 + mg * 8;
    const f32x4 fa = *(const f32x4*)&feat1[base];
    const f32x4 fbv = *(const f32x4*)&feat1[base + 4];
    f32x4 o0, o1;
#pragma unroll
    for (int j = 0; j < 4; ++j) {
      o0[j] = gam * v[j] + fa[j];
      o1[j] = gam * v[4 + j] + fbv[j];
    }
    *(f32x4*)&out[base] = o0;
    *(f32x4*)&out[base + 4] = o1;
  }
}

// ---------------------------------------------------------------------------
// Launch
// ---------------------------------------------------------------------------
extern "C" void kernel_launch(void* const* d_in, const int* in_sizes, int n_in,
                              void* d_out, int out_size, void* d_ws,
                              size_t ws_size, hipStream_t stream) {
  const float* feat1 = (const float*)d_in[0];
  const float* feat2 = (const float*)d_in[1];
  const float* Wq = (const float*)d_in[2];
  const float* bq = (const float*)d_in[3];
  const float* Wk = (const float*)d_in[4];
  const float* bk = (const float*)d_in[5];
  const float* Wv = (const float*)d_in[6];
  const float* bv = (const float*)d_in[7];
  const float* gamma = (const float*)d_in[8];
  float* out = (float*)d_out;
  char* ws = (char*)d_ws;

  const size_t need4 = 44433408;  // proven ws >= 44466176 (round-5 KS=2 ran)
  if (ws_size >= need4) {
    // KS=4 layout. f1T/f2T/W overlay Opart (dead before attn writes it).
    short* Opart = (short*)(ws + 0);          // 32 MiB [4][4][256][4096] bf16
    short* f1T  = (short*)(ws + 0);           //  8 MiB (overlay)
    short* f2T  = (short*)(ws + 8388608);     //  8 MiB (overlay)
    short* Wq_b = (short*)(ws + 16777216);    // 16 KiB (overlay)
    short* Wk_b = (short*)(ws + 16793600);
    short* Wv_b = (short*)(ws + 16809984);    // 128 KiB (overlay)
    short* q_ws = (short*)(ws + 33554432);    // 1 MiB
    short* k_ws = (short*)(ws + 34603008);    // 1 MiB
    short* v_ws = (short*)(ws + 35651584);    // 8 MiB
    float* mlm  = (float*)(ws + 44040192);    // 256 KiB f32
    short* mll  = (short*)(ws + 44302336);    // 128 KiB bf16

    prep_transpose<<<2048, 256, 0, stream>>>(feat1, feat2, f1T, f2T);
    prep_weights<<<80, 256, 0, stream>>>(Wq, Wk, Wv, Wq_b, Wk_b, Wv_b);
    proj_qkv<<<256, 256, 0, stream>>>(f1T, f2T, Wq_b, bq, Wk_b, bk, Wv_b, bv,
                                      q_ws, k_ws, v_ws);
    attn_kernel<4><<<512, 256, 0, stream>>>(q_ws, k_ws, v_ws, Opart, mlm, mll);
    combine_kernel<4><<<256, 256, 0, stream>>>(Opart, mlm, mll, feat1, gamma,
                                               out);
  } else {
    // KS=2 fallback (~27.6 MiB).
    short* Opart = (short*)(ws + 0);          // 16 MiB
    short* f1T  = (short*)(ws + 0);           // overlay
    short* f2T  = (short*)(ws + 8388608);     // overlay
    short* Wq_b = (short*)(ws + 16777216);
    short* Wk_b = (short*)(ws + 16793600);
    short* Wv_b = (short*)(ws + 16809984);
    short* q_ws = (short*)(ws + 16941056);
    short* k_ws = (short*)(ws + 17989632);
    short* v_ws = (short*)(ws + 19038208);
    float* mlm  = (float*)(ws + 27426816);
    short* mll  = (short*)(ws + 27557888);

    prep_transpose<<<2048, 256, 0, stream>>>(feat1, feat2, f1T, f2T);
    prep_weights<<<80, 256, 0, stream>>>(Wq, Wk, Wv, Wq_b, Wk_b, Wv_b);
    proj_qkv<<<256, 256, 0, stream>>>(f1T, f2T, Wq_b, bq, Wk_b, bk, Wv_b, bv,
                                      q_ws, k_ws, v_ws);
    attn_kernel<2><<<256, 256, 0, stream>>>(q_ws, k_ws, v_ws, Opart, mlm, mll);
    combine_kernel<2><<<256, 256, 0, stream>>>(Opart, mlm, mll, feat1, gamma,
                                               out);
  }
}